// Round 1
// baseline (1218.743 us; speedup 1.0000x reference)
//
#include <hip/hip_runtime.h>
#include <hip/hip_bf16.h>

#define N_NODES 50000
#define N_EDGES 1600000
#define ET (N_EDGES + N_NODES)
#define G_GRAPHS 128

// ---------------- small utility kernels ----------------

__global__ void ea_sum_kernel(const float* __restrict__ ea, float* __restrict__ out, int n)
{
    float s = 0.f;
    for (int i = blockIdx.x * blockDim.x + threadIdx.x; i < n; i += gridDim.x * blockDim.x)
        s += ea[i];
    #pragma unroll
    for (int off = 32; off; off >>= 1) s += __shfl_xor(s, off);
    if ((threadIdx.x & 63) == 0) atomicAdd(out, s);
}

// ws scalars layout: [0]=ea_sum [1]=ea_mean [2..5]=c1[4] [6]=c2
__global__ void scalars_kernel(float* __restrict__ ws,
                               const float* __restrict__ We1, const float* __restrict__ ae1,
                               const float* __restrict__ We2, const float* __restrict__ ae2)
{
    if (threadIdx.x == 0 && blockIdx.x == 0) {
        ws[1] = ws[0] / (float)N_EDGES;
        for (int h = 0; h < 4; ++h) {
            float c = 0.f;
            for (int o = 0; o < 64; ++o) c += We1[h * 64 + o] * ae1[h * 64 + o];
            ws[2 + h] = c;
        }
        float c2 = 0.f;
        for (int o = 0; o < 64; ++o) c2 += We2[o] * ae2[o];
        ws[6] = c2;
    }
}

__global__ void deg_kernel(const int* __restrict__ ei, int* __restrict__ deg)
{
    for (int e = blockIdx.x * blockDim.x + threadIdx.x; e < ET; e += gridDim.x * blockDim.x) {
        int dst = (e < N_EDGES) ? ei[N_EDGES + e] : (e - N_EDGES);
        atomicAdd(&deg[dst], 1);
    }
}

__global__ __launch_bounds__(1024) void scan_kernel(const int* __restrict__ deg,
                                                    int* __restrict__ rowstart,
                                                    int* __restrict__ cursor)
{
    __shared__ int ssum[1024];
    const int C = (N_NODES + 1023) / 1024;   // 49
    int tid = threadIdx.x;
    int c0 = tid * C, c1 = min(c0 + C, N_NODES);
    int s = 0;
    for (int i = c0; i < c1; ++i) s += deg[i];
    ssum[tid] = s;
    __syncthreads();
    for (int off = 1; off < 1024; off <<= 1) {
        int v = (tid >= off) ? ssum[tid - off] : 0;
        __syncthreads();
        ssum[tid] += v;
        __syncthreads();
    }
    int run = ssum[tid] - s;  // exclusive prefix
    for (int i = c0; i < c1; ++i) { rowstart[i] = run; cursor[i] = run; run += deg[i]; }
    if (tid == 1023) rowstart[N_NODES] = ET;
}

__global__ void fill_kernel(const int* __restrict__ ei, const float* __restrict__ ea,
                            const float* __restrict__ ws, int* __restrict__ cursor,
                            int* __restrict__ csr_src, float* __restrict__ csr_ea)
{
    float mean = ws[1];
    for (int e = blockIdx.x * blockDim.x + threadIdx.x; e < ET; e += gridDim.x * blockDim.x) {
        int src, dst; float v;
        if (e < N_EDGES) { src = ei[e]; dst = ei[N_EDGES + e]; v = ea[e]; }
        else             { src = dst = e - N_EDGES; v = mean; }
        int pos = atomicAdd(&cursor[dst], 1);
        csr_src[pos] = src;
        csr_ea[pos]  = v;
    }
}

// ---------------- f32 tiled GEMM: C[M,NC] = A[M,K] @ B[K,NC] ----------------
// BM=BN=64, block 256 (16x16), 4x4 per thread, BK=16. K%16==0, NC%64==0.
template <int BK>
__global__ __launch_bounds__(256) void gemm_tile(const float* __restrict__ A,
                                                 const float* __restrict__ B,
                                                 float* __restrict__ C,
                                                 int M, int K, int NC)
{
    __shared__ __align__(16) float As[BK][64];
    __shared__ __align__(16) float Bs[BK][64];
    int tid = threadIdx.x;
    int tx = tid & 15, ty = tid >> 4;
    int rowBase = blockIdx.y * 64;
    int colBase = blockIdx.x * 64;
    float acc[4][4] = {};
    for (int k0 = 0; k0 < K; k0 += BK) {
        {   // A tile: 64 x BK (transposed into As[k][row])
            int r  = tid >> 2;
            int kq = (tid & 3) * 4;
            int grow = rowBase + r;
            float4 v = make_float4(0.f, 0.f, 0.f, 0.f);
            if (grow < M) v = *(const float4*)&A[(size_t)grow * K + k0 + kq];
            As[kq + 0][r] = v.x; As[kq + 1][r] = v.y;
            As[kq + 2][r] = v.z; As[kq + 3][r] = v.w;
        }
        {   // B tile: BK x 64
            int kk = tid >> 4;
            int c  = (tid & 15) * 4;
            float4 v = *(const float4*)&B[(size_t)(k0 + kk) * NC + colBase + c];
            *(float4*)&Bs[kk][c] = v;
        }
        __syncthreads();
        #pragma unroll
        for (int k = 0; k < BK; ++k) {
            float4 a4 = *(const float4*)&As[k][ty * 4];
            float4 b4 = *(const float4*)&Bs[k][tx * 4];
            float aa[4] = {a4.x, a4.y, a4.z, a4.w};
            float bb[4] = {b4.x, b4.y, b4.z, b4.w};
            #pragma unroll
            for (int i = 0; i < 4; ++i)
                #pragma unroll
                for (int j = 0; j < 4; ++j)
                    acc[i][j] = fmaf(aa[i], bb[j], acc[i][j]);
        }
        __syncthreads();
    }
    #pragma unroll
    for (int i = 0; i < 4; ++i) {
        int grow = rowBase + ty * 4 + i;
        if (grow < M) {
            float4 o = make_float4(acc[i][0], acc[i][1], acc[i][2], acc[i][3]);
            *(float4*)&C[(size_t)grow * NC + colBase + tx * 4] = o;
        }
    }
}

// ---------------- per-node alpha projections ----------------

__global__ __launch_bounds__(256) void alphas1_kernel(const float* __restrict__ h1,
                                                      const float* __restrict__ as1,
                                                      const float* __restrict__ ad1,
                                                      float* __restrict__ asrc,
                                                      float* __restrict__ adst)
{
    int wid  = (blockIdx.x * blockDim.x + threadIdx.x) >> 6;
    int lane = threadIdx.x & 63;
    if (wid >= N_NODES) return;
    const float* hr = h1 + (size_t)wid * 256;
    float sa[4], da[4];
    #pragma unroll
    for (int j = 0; j < 4; ++j) {
        float v = hr[j * 64 + lane];
        sa[j] = v * as1[j * 64 + lane];
        da[j] = v * ad1[j * 64 + lane];
    }
    #pragma unroll
    for (int off = 32; off; off >>= 1)
        #pragma unroll
        for (int j = 0; j < 4; ++j) {
            sa[j] += __shfl_xor(sa[j], off);
            da[j] += __shfl_xor(da[j], off);
        }
    if (lane == 0)
        #pragma unroll
        for (int j = 0; j < 4; ++j) {
            asrc[(size_t)wid * 4 + j] = sa[j];
            adst[(size_t)wid * 4 + j] = da[j];
        }
}

__global__ __launch_bounds__(256) void alphas2_kernel(const float* __restrict__ h2,
                                                      const float* __restrict__ as2,
                                                      const float* __restrict__ ad2,
                                                      float* __restrict__ asrc,
                                                      float* __restrict__ adst)
{
    int wid  = (blockIdx.x * blockDim.x + threadIdx.x) >> 6;
    int lane = threadIdx.x & 63;
    if (wid >= N_NODES) return;
    float v  = h2[(size_t)wid * 64 + lane];
    float sa = v * as2[lane];
    float da = v * ad2[lane];
    #pragma unroll
    for (int off = 32; off; off >>= 1) {
        sa += __shfl_xor(sa, off);
        da += __shfl_xor(da, off);
    }
    if (lane == 0) { asrc[wid] = sa; adst[wid] = da; }
}

// ---------------- layer 1: softmax + aggregation, one wave per dst node ----------------

__global__ __launch_bounds__(256) void agg1_kernel(const int* __restrict__ rowstart,
                                                   const int* __restrict__ csr_src,
                                                   const float* __restrict__ csr_ea,
                                                   const float* __restrict__ asrc,
                                                   const float* __restrict__ adst,
                                                   const float* __restrict__ ws,
                                                   const float* __restrict__ h1,
                                                   const float* __restrict__ b1,
                                                   float* __restrict__ h1r)
{
    int wid  = (blockIdx.x * blockDim.x + threadIdx.x) >> 6;
    int lane = threadIdx.x & 63;
    if (wid >= N_NODES) return;
    int rs = rowstart[wid], re = rowstart[wid + 1];
    float c[4], ad[4];
    #pragma unroll
    for (int h = 0; h < 4; ++h) { c[h] = ws[2 + h]; ad[h] = adst[(size_t)wid * 4 + h]; }

    // phase 1: online max+sum per head, edges strided across lanes
    float m[4] = {-1e30f, -1e30f, -1e30f, -1e30f}, s[4] = {0.f, 0.f, 0.f, 0.f};
    for (int p = rs + lane; p < re; p += 64) {
        int src  = csr_src[p];
        float ev = csr_ea[p];
        float4 av = *(const float4*)&asrc[(size_t)src * 4];
        float a[4] = {av.x + ad[0] + ev * c[0], av.y + ad[1] + ev * c[1],
                      av.z + ad[2] + ev * c[2], av.w + ad[3] + ev * c[3]};
        #pragma unroll
        for (int h = 0; h < 4; ++h) {
            float x  = a[h] > 0.f ? a[h] : 0.2f * a[h];
            float nm = fmaxf(m[h], x);
            s[h] = s[h] * __expf(m[h] - nm) + __expf(x - nm);
            m[h] = nm;
        }
    }
    #pragma unroll
    for (int off = 1; off < 64; off <<= 1)
        #pragma unroll
        for (int h = 0; h < 4; ++h) {
            float om = __shfl_xor(m[h], off);
            float os = __shfl_xor(s[h], off);
            float nm = fmaxf(m[h], om);
            s[h] = s[h] * __expf(m[h] - nm) + os * __expf(om - nm);
            m[h] = nm;
        }
    float inv[4];
    #pragma unroll
    for (int h = 0; h < 4; ++h) inv[h] = 1.0f / (s[h] + 1e-16f);

    // phase 2: channel-parallel accumulate (lane owns channel lane+64h)
    float acc0 = 0.f, acc1 = 0.f, acc2 = 0.f, acc3 = 0.f;
    for (int p = rs; p < re; ++p) {
        int src  = csr_src[p];
        float ev = csr_ea[p];
        float4 av = *(const float4*)&asrc[(size_t)src * 4];
        float a0 = av.x + ad[0] + ev * c[0]; a0 = a0 > 0.f ? a0 : 0.2f * a0;
        float a1 = av.y + ad[1] + ev * c[1]; a1 = a1 > 0.f ? a1 : 0.2f * a1;
        float a2 = av.z + ad[2] + ev * c[2]; a2 = a2 > 0.f ? a2 : 0.2f * a2;
        float a3 = av.w + ad[3] + ev * c[3]; a3 = a3 > 0.f ? a3 : 0.2f * a3;
        float w0 = __expf(a0 - m[0]) * inv[0];
        float w1 = __expf(a1 - m[1]) * inv[1];
        float w2 = __expf(a2 - m[2]) * inv[2];
        float w3 = __expf(a3 - m[3]) * inv[3];
        const float* hr = h1 + (size_t)src * 256;
        acc0 = fmaf(hr[lane],       w0, acc0);
        acc1 = fmaf(hr[64 + lane],  w1, acc1);
        acc2 = fmaf(hr[128 + lane], w2, acc2);
        acc3 = fmaf(hr[192 + lane], w3, acc3);
    }
    float* o = h1r + (size_t)wid * 256;
    o[lane]       = fmaxf(acc0 + b1[lane],       0.f);
    o[64 + lane]  = fmaxf(acc1 + b1[64 + lane],  0.f);
    o[128 + lane] = fmaxf(acc2 + b1[128 + lane], 0.f);
    o[192 + lane] = fmaxf(acc3 + b1[192 + lane], 0.f);
}

// ---------------- layer 2 (H=1) + fused mean-pool scatter ----------------

__global__ __launch_bounds__(256) void agg2_kernel(const int* __restrict__ rowstart,
                                                   const int* __restrict__ csr_src,
                                                   const float* __restrict__ csr_ea,
                                                   const float* __restrict__ asrc,
                                                   const float* __restrict__ adst,
                                                   const float* __restrict__ ws,
                                                   const float* __restrict__ h2pre,
                                                   const float* __restrict__ b2,
                                                   const int* __restrict__ bidx,
                                                   float* __restrict__ pool_s,
                                                   float* __restrict__ pool_cnt)
{
    int wid  = (blockIdx.x * blockDim.x + threadIdx.x) >> 6;
    int lane = threadIdx.x & 63;
    if (wid >= N_NODES) return;
    int rs = rowstart[wid], re = rowstart[wid + 1];
    float c2 = ws[6];
    float ad = adst[wid];
    float m = -1e30f, s = 0.f;
    for (int p = rs + lane; p < re; p += 64) {
        int src  = csr_src[p];
        float ev = csr_ea[p];
        float a  = asrc[src] + ad + ev * c2;
        a = a > 0.f ? a : 0.2f * a;
        float nm = fmaxf(m, a);
        s = s * __expf(m - nm) + __expf(a - nm);
        m = nm;
    }
    #pragma unroll
    for (int off = 1; off < 64; off <<= 1) {
        float om = __shfl_xor(m, off);
        float os = __shfl_xor(s, off);
        float nm = fmaxf(m, om);
        s = s * __expf(m - nm) + os * __expf(om - nm);
        m = nm;
    }
    float inv = 1.0f / (s + 1e-16f);
    float acc = 0.f;
    for (int p = rs; p < re; ++p) {
        int src  = csr_src[p];
        float ev = csr_ea[p];
        float a  = asrc[src] + ad + ev * c2;
        a = a > 0.f ? a : 0.2f * a;
        float w = __expf(a - m) * inv;
        acc = fmaf(h2pre[(size_t)src * 64 + lane], w, acc);
    }
    float val = acc + b2[lane];
    int g = bidx[wid];
    atomicAdd(&pool_s[(size_t)g * 64 + lane], val);
    if (lane == 0) atomicAdd(&pool_cnt[g], 1.f);
}

// ---------------- MLP head: one wave per graph ----------------

__global__ __launch_bounds__(64) void mlp_kernel(const float* __restrict__ pool_s,
                                                 const float* __restrict__ pool_cnt,
                                                 const float* __restrict__ Wl1,
                                                 const float* __restrict__ bl1,
                                                 const float* __restrict__ lng,
                                                 const float* __restrict__ lnb,
                                                 const float* __restrict__ Wl2,
                                                 const float* __restrict__ bl2,
                                                 float* __restrict__ out)
{
    int g = blockIdx.x, l = threadIdx.x;
    __shared__ float gs[64], zs[64];
    float cnt = fmaxf(pool_cnt[g], 1.f);
    gs[l] = pool_s[(size_t)g * 64 + l] / cnt;
    __syncthreads();
    float z = bl1[l];
    for (int k = 0; k < 64; ++k) z = fmaf(gs[k], Wl1[k * 64 + l], z);
    z = fmaxf(z, 0.f);
    float sum = z;
    #pragma unroll
    for (int off = 32; off; off >>= 1) sum += __shfl_xor(sum, off);
    float mu = sum * (1.f / 64.f);
    float d  = z - mu;
    float vs = d * d;
    #pragma unroll
    for (int off = 32; off; off >>= 1) vs += __shfl_xor(vs, off);
    float var = vs * (1.f / 64.f);
    z = d * rsqrtf(var + 1e-5f) * lng[l] + lnb[l];
    zs[l] = z;
    __syncthreads();
    if (l < 16) {
        float o = bl2[l];
        for (int k = 0; k < 64; ++k) o = fmaf(zs[k], Wl2[k * 16 + l], o);
        out[g * 16 + l] = o;
    }
}

__global__ void copy_ea_kernel(const float* __restrict__ ea, float* __restrict__ out)
{
    for (int i = blockIdx.x * blockDim.x + threadIdx.x; i < N_EDGES; i += gridDim.x * blockDim.x)
        out[i] = ea[i];
}

// ---------------- launch ----------------

extern "C" void kernel_launch(void* const* d_in, const int* in_sizes, int n_in,
                              void* d_out, int out_size, void* d_ws, size_t ws_size,
                              hipStream_t stream)
{
    const float* x    = (const float*)d_in[0];
    const int*   ei   = (const int*)d_in[1];
    const float* ea   = (const float*)d_in[2];
    const int*   bidx = (const int*)d_in[3];
    const float* W1   = (const float*)d_in[4];
    const float* as1  = (const float*)d_in[5];
    const float* ad1  = (const float*)d_in[6];
    const float* We1  = (const float*)d_in[7];
    const float* ae1  = (const float*)d_in[8];
    const float* b1   = (const float*)d_in[9];
    const float* W2   = (const float*)d_in[10];
    const float* as2  = (const float*)d_in[11];
    const float* ad2  = (const float*)d_in[12];
    const float* We2  = (const float*)d_in[13];
    const float* ae2  = (const float*)d_in[14];
    const float* b2   = (const float*)d_in[15];
    const float* Wl1  = (const float*)d_in[16];
    const float* bl1  = (const float*)d_in[17];
    const float* lng  = (const float*)d_in[18];
    const float* lnb  = (const float*)d_in[19];
    const float* Wl2  = (const float*)d_in[20];
    const float* bl2  = (const float*)d_in[21];
    float* out = (float*)d_out;

    char* w = (char*)d_ws;
    // zeroed region: scalars(64) | deg(200000) | pool_s(32768) | pool_cnt(512)
    float* scalars  = (float*)(w + 0);
    int*   deg      = (int*)  (w + 64);
    float* pool_s   = (float*)(w + 200064);
    float* pool_cnt = (float*)(w + 232832);
    const size_t zbytes = 233344;
    int*   rowstart = (int*)  (w + 233344);
    int*   cursor   = (int*)  (w + 433360);
    int*   csr_src  = (int*)  (w + 633360);
    float* csr_ea   = (float*)(w + 7233360);
    float* asrc1    = (float*)(w + 13833360);
    float* adst1    = (float*)(w + 14633360);
    float* asrc2    = (float*)(w + 15433360);
    float* adst2    = (float*)(w + 15633360);
    float* h1       = (float*)(w + 15833360);
    float* h1r      = (float*)(w + 67033360);
    float* h2pre    = (float*)(w + 118233360);

    hipMemsetAsync(d_ws, 0, zbytes, stream);
    ea_sum_kernel<<<512, 256, 0, stream>>>(ea, scalars, N_EDGES);
    scalars_kernel<<<1, 64, 0, stream>>>(scalars, We1, ae1, We2, ae2);
    deg_kernel<<<1024, 256, 0, stream>>>(ei, deg);
    scan_kernel<<<1, 1024, 0, stream>>>(deg, rowstart, cursor);
    fill_kernel<<<1024, 256, 0, stream>>>(ei, ea, scalars, cursor, csr_src, csr_ea);

    { dim3 g(4, 782);  gemm_tile<16><<<g, 256, 0, stream>>>(x,   W1, h1,    N_NODES, 128, 256); }
    alphas1_kernel<<<12500, 256, 0, stream>>>(h1, as1, ad1, asrc1, adst1);
    agg1_kernel<<<12500, 256, 0, stream>>>(rowstart, csr_src, csr_ea, asrc1, adst1,
                                           scalars, h1, b1, h1r);
    { dim3 g(1, 782);  gemm_tile<16><<<g, 256, 0, stream>>>(h1r, W2, h2pre, N_NODES, 256, 64); }
    alphas2_kernel<<<12500, 256, 0, stream>>>(h2pre, as2, ad2, asrc2, adst2);
    agg2_kernel<<<12500, 256, 0, stream>>>(rowstart, csr_src, csr_ea, asrc2, adst2,
                                           scalars, h2pre, b2, bidx, pool_s, pool_cnt);
    mlp_kernel<<<G_GRAPHS, 64, 0, stream>>>(pool_s, pool_cnt, Wl1, bl1, lng, lnb, Wl2, bl2, out);
    copy_ea_kernel<<<2048, 256, 0, stream>>>(ea, out + 2048);
}

// Round 2
// 1113.012 us; speedup vs baseline: 1.0950x; 1.0950x over previous
//
#include <hip/hip_runtime.h>
#include <hip/hip_bf16.h>

#define N_NODES 50000
#define N_EDGES 1600000
#define ET (N_EDGES + N_NODES)
#define G_GRAPHS 128

// ---------------- small utility kernels ----------------

__global__ void ea_sum_kernel(const float* __restrict__ ea, float* __restrict__ out, int n)
{
    float s = 0.f;
    for (int i = blockIdx.x * blockDim.x + threadIdx.x; i < n; i += gridDim.x * blockDim.x)
        s += ea[i];
    #pragma unroll
    for (int off = 32; off; off >>= 1) s += __shfl_xor(s, off);
    if ((threadIdx.x & 63) == 0) atomicAdd(out, s);
}

// ws scalars layout: [0]=ea_sum [1]=ea_mean [2..5]=c1[4] [6]=c2
__global__ void scalars_kernel(float* __restrict__ ws,
                               const float* __restrict__ We1, const float* __restrict__ ae1,
                               const float* __restrict__ We2, const float* __restrict__ ae2)
{
    if (threadIdx.x == 0 && blockIdx.x == 0) {
        ws[1] = ws[0] / (float)N_EDGES;
        for (int h = 0; h < 4; ++h) {
            float c = 0.f;
            for (int o = 0; o < 64; ++o) c += We1[h * 64 + o] * ae1[h * 64 + o];
            ws[2 + h] = c;
        }
        float c2 = 0.f;
        for (int o = 0; o < 64; ++o) c2 += We2[o] * ae2[o];
        ws[6] = c2;
    }
}

__global__ void deg_kernel(const int* __restrict__ ei, int* __restrict__ deg)
{
    for (int e = blockIdx.x * blockDim.x + threadIdx.x; e < ET; e += gridDim.x * blockDim.x) {
        int dst = (e < N_EDGES) ? ei[N_EDGES + e] : (e - N_EDGES);
        atomicAdd(&deg[dst], 1);
    }
}

__global__ __launch_bounds__(1024) void scan_kernel(const int* __restrict__ deg,
                                                    int* __restrict__ rowstart,
                                                    int* __restrict__ cursor)
{
    __shared__ int ssum[1024];
    const int C = (N_NODES + 1023) / 1024;   // 49
    int tid = threadIdx.x;
    int c0 = tid * C, c1 = min(c0 + C, N_NODES);
    int s = 0;
    for (int i = c0; i < c1; ++i) s += deg[i];
    ssum[tid] = s;
    __syncthreads();
    for (int off = 1; off < 1024; off <<= 1) {
        int v = (tid >= off) ? ssum[tid - off] : 0;
        __syncthreads();
        ssum[tid] += v;
        __syncthreads();
    }
    int run = ssum[tid] - s;  // exclusive prefix
    for (int i = c0; i < c1; ++i) { rowstart[i] = run; cursor[i] = run; run += deg[i]; }
    if (tid == 1023) rowstart[N_NODES] = ET;
}

__global__ void fill_kernel(const int* __restrict__ ei, const float* __restrict__ ea,
                            const float* __restrict__ ws, int* __restrict__ cursor,
                            int* __restrict__ csr_src, float* __restrict__ csr_ea)
{
    float mean = ws[1];
    for (int e = blockIdx.x * blockDim.x + threadIdx.x; e < ET; e += gridDim.x * blockDim.x) {
        int src, dst; float v;
        if (e < N_EDGES) { src = ei[e]; dst = ei[N_EDGES + e]; v = ea[e]; }
        else             { src = dst = e - N_EDGES; v = mean; }
        int pos = atomicAdd(&cursor[dst], 1);
        csr_src[pos] = src;
        csr_ea[pos]  = v;
    }
}

// ---------------- f32 tiled GEMM: C[M,NC] = A[M,K] @ B[K,NC] ----------------
template <int BK>
__global__ __launch_bounds__(256) void gemm_tile(const float* __restrict__ A,
                                                 const float* __restrict__ B,
                                                 float* __restrict__ C,
                                                 int M, int K, int NC)
{
    __shared__ __align__(16) float As[BK][64];
    __shared__ __align__(16) float Bs[BK][64];
    int tid = threadIdx.x;
    int tx = tid & 15, ty = tid >> 4;
    int rowBase = blockIdx.y * 64;
    int colBase = blockIdx.x * 64;
    float acc[4][4] = {};
    for (int k0 = 0; k0 < K; k0 += BK) {
        {
            int r  = tid >> 2;
            int kq = (tid & 3) * 4;
            int grow = rowBase + r;
            float4 v = make_float4(0.f, 0.f, 0.f, 0.f);
            if (grow < M) v = *(const float4*)&A[(size_t)grow * K + k0 + kq];
            As[kq + 0][r] = v.x; As[kq + 1][r] = v.y;
            As[kq + 2][r] = v.z; As[kq + 3][r] = v.w;
        }
        {
            int kk = tid >> 4;
            int c  = (tid & 15) * 4;
            float4 v = *(const float4*)&B[(size_t)(k0 + kk) * NC + colBase + c];
            *(float4*)&Bs[kk][c] = v;
        }
        __syncthreads();
        #pragma unroll
        for (int k = 0; k < BK; ++k) {
            float4 a4 = *(const float4*)&As[k][ty * 4];
            float4 b4 = *(const float4*)&Bs[k][tx * 4];
            float aa[4] = {a4.x, a4.y, a4.z, a4.w};
            float bb[4] = {b4.x, b4.y, b4.z, b4.w};
            #pragma unroll
            for (int i = 0; i < 4; ++i)
                #pragma unroll
                for (int j = 0; j < 4; ++j)
                    acc[i][j] = fmaf(aa[i], bb[j], acc[i][j]);
        }
        __syncthreads();
    }
    #pragma unroll
    for (int i = 0; i < 4; ++i) {
        int grow = rowBase + ty * 4 + i;
        if (grow < M) {
            float4 o = make_float4(acc[i][0], acc[i][1], acc[i][2], acc[i][3]);
            *(float4*)&C[(size_t)grow * NC + colBase + tx * 4] = o;
        }
    }
}

// ---------------- per-node alpha projections ----------------

__global__ __launch_bounds__(256) void alphas1_kernel(const float* __restrict__ h1,
                                                      const float* __restrict__ as1,
                                                      const float* __restrict__ ad1,
                                                      float* __restrict__ asrc,
                                                      float* __restrict__ adst)
{
    int wid  = (blockIdx.x * blockDim.x + threadIdx.x) >> 6;
    int lane = threadIdx.x & 63;
    if (wid >= N_NODES) return;
    const float* hr = h1 + (size_t)wid * 256;
    float sa[4], da[4];
    #pragma unroll
    for (int j = 0; j < 4; ++j) {
        float v = hr[j * 64 + lane];
        sa[j] = v * as1[j * 64 + lane];
        da[j] = v * ad1[j * 64 + lane];
    }
    #pragma unroll
    for (int off = 32; off; off >>= 1)
        #pragma unroll
        for (int j = 0; j < 4; ++j) {
            sa[j] += __shfl_xor(sa[j], off);
            da[j] += __shfl_xor(da[j], off);
        }
    if (lane == 0)
        #pragma unroll
        for (int j = 0; j < 4; ++j) {
            asrc[(size_t)wid * 4 + j] = sa[j];
            adst[(size_t)wid * 4 + j] = da[j];
        }
}

__global__ __launch_bounds__(256) void alphas2_kernel(const float* __restrict__ h2,
                                                      const float* __restrict__ as2,
                                                      const float* __restrict__ ad2,
                                                      float* __restrict__ asrc,
                                                      float* __restrict__ adst)
{
    int wid  = (blockIdx.x * blockDim.x + threadIdx.x) >> 6;
    int lane = threadIdx.x & 63;
    if (wid >= N_NODES) return;
    float v  = h2[(size_t)wid * 64 + lane];
    float sa = v * as2[lane];
    float da = v * ad2[lane];
    #pragma unroll
    for (int off = 32; off; off >>= 1) {
        sa += __shfl_xor(sa, off);
        da += __shfl_xor(da, off);
    }
    if (lane == 0) { asrc[wid] = sa; adst[wid] = da; }
}

// ---------------- layer 1: softmax + aggregation, one wave per dst node ----------------

__global__ __launch_bounds__(256) void agg1_kernel(const int* __restrict__ rowstart,
                                                   const int* __restrict__ csr_src,
                                                   const float* __restrict__ csr_ea,
                                                   const float* __restrict__ asrc,
                                                   const float* __restrict__ adst,
                                                   const float* __restrict__ ws,
                                                   const float* __restrict__ h1,
                                                   const float* __restrict__ b1,
                                                   float* __restrict__ h1r)
{
    int wid  = (blockIdx.x * blockDim.x + threadIdx.x) >> 6;
    int lane = threadIdx.x & 63;
    if (wid >= N_NODES) return;
    int rs = rowstart[wid], re = rowstart[wid + 1];
    float c[4], ad[4];
    #pragma unroll
    for (int h = 0; h < 4; ++h) { c[h] = ws[2 + h]; ad[h] = adst[(size_t)wid * 4 + h]; }

    // phase 1: online max+sum per head, edges strided across lanes
    float m[4] = {-1e30f, -1e30f, -1e30f, -1e30f}, s[4] = {0.f, 0.f, 0.f, 0.f};
    for (int p = rs + lane; p < re; p += 64) {
        int src  = csr_src[p];
        float ev = csr_ea[p];
        float4 av = *(const float4*)&asrc[(size_t)src * 4];
        float a[4] = {av.x + ad[0] + ev * c[0], av.y + ad[1] + ev * c[1],
                      av.z + ad[2] + ev * c[2], av.w + ad[3] + ev * c[3]};
        #pragma unroll
        for (int h = 0; h < 4; ++h) {
            float x  = a[h] > 0.f ? a[h] : 0.2f * a[h];
            float nm = fmaxf(m[h], x);
            s[h] = s[h] * __expf(m[h] - nm) + __expf(x - nm);
            m[h] = nm;
        }
    }
    #pragma unroll
    for (int off = 1; off < 64; off <<= 1)
        #pragma unroll
        for (int h = 0; h < 4; ++h) {
            float om = __shfl_xor(m[h], off);
            float os = __shfl_xor(s[h], off);
            float nm = fmaxf(m[h], om);
            s[h] = s[h] * __expf(m[h] - nm) + os * __expf(om - nm);
            m[h] = nm;
        }
    float inv[4];
    #pragma unroll
    for (int h = 0; h < 4; ++h) inv[h] = 1.0f / (s[h] + 1e-16f);

    // phase 2: lane owns channels 4*lane..4*lane+3 => head hh = lane>>4.
    int hh = lane >> 4;
    float ad_s = hh < 2 ? (hh == 0 ? ad[0] : ad[1]) : (hh == 2 ? ad[2] : ad[3]);
    float c_s  = hh < 2 ? (hh == 0 ? c[0]  : c[1])  : (hh == 2 ? c[2]  : c[3]);
    float m_s  = hh < 2 ? (hh == 0 ? m[0]  : m[1])  : (hh == 2 ? m[2]  : m[3]);
    float i_s  = hh < 2 ? (hh == 0 ? inv[0]: inv[1]): (hh == 2 ? inv[2]: inv[3]);

    float4 acc = make_float4(0.f, 0.f, 0.f, 0.f);
    int p = rs;
    int nmain = rs + ((re - rs) & ~3);
    for (; p < nmain; p += 4) {
        int s0 = csr_src[p],     s1 = csr_src[p + 1];
        int s2 = csr_src[p + 2], s3 = csr_src[p + 3];
        float e0 = csr_ea[p],     e1 = csr_ea[p + 1];
        float e2 = csr_ea[p + 2], e3 = csr_ea[p + 3];
        float4 r0 = *(const float4*)&h1[(size_t)s0 * 256 + lane * 4];
        float4 r1 = *(const float4*)&h1[(size_t)s1 * 256 + lane * 4];
        float4 r2 = *(const float4*)&h1[(size_t)s2 * 256 + lane * 4];
        float4 r3 = *(const float4*)&h1[(size_t)s3 * 256 + lane * 4];
        float a0 = asrc[(size_t)s0 * 4 + hh] + ad_s + e0 * c_s; a0 = a0 > 0.f ? a0 : 0.2f * a0;
        float a1 = asrc[(size_t)s1 * 4 + hh] + ad_s + e1 * c_s; a1 = a1 > 0.f ? a1 : 0.2f * a1;
        float a2 = asrc[(size_t)s2 * 4 + hh] + ad_s + e2 * c_s; a2 = a2 > 0.f ? a2 : 0.2f * a2;
        float a3 = asrc[(size_t)s3 * 4 + hh] + ad_s + e3 * c_s; a3 = a3 > 0.f ? a3 : 0.2f * a3;
        float w0 = __expf(a0 - m_s) * i_s;
        float w1 = __expf(a1 - m_s) * i_s;
        float w2 = __expf(a2 - m_s) * i_s;
        float w3 = __expf(a3 - m_s) * i_s;
        acc.x = fmaf(r0.x, w0, fmaf(r1.x, w1, fmaf(r2.x, w2, fmaf(r3.x, w3, acc.x))));
        acc.y = fmaf(r0.y, w0, fmaf(r1.y, w1, fmaf(r2.y, w2, fmaf(r3.y, w3, acc.y))));
        acc.z = fmaf(r0.z, w0, fmaf(r1.z, w1, fmaf(r2.z, w2, fmaf(r3.z, w3, acc.z))));
        acc.w = fmaf(r0.w, w0, fmaf(r1.w, w1, fmaf(r2.w, w2, fmaf(r3.w, w3, acc.w))));
    }
    for (; p < re; ++p) {
        int s0 = csr_src[p];
        float e0 = csr_ea[p];
        float4 r0 = *(const float4*)&h1[(size_t)s0 * 256 + lane * 4];
        float a0 = asrc[(size_t)s0 * 4 + hh] + ad_s + e0 * c_s; a0 = a0 > 0.f ? a0 : 0.2f * a0;
        float w0 = __expf(a0 - m_s) * i_s;
        acc.x = fmaf(r0.x, w0, acc.x);
        acc.y = fmaf(r0.y, w0, acc.y);
        acc.z = fmaf(r0.z, w0, acc.z);
        acc.w = fmaf(r0.w, w0, acc.w);
    }
    float4 bb = *(const float4*)&b1[lane * 4];
    float4 o;
    o.x = fmaxf(acc.x + bb.x, 0.f);
    o.y = fmaxf(acc.y + bb.y, 0.f);
    o.z = fmaxf(acc.z + bb.z, 0.f);
    o.w = fmaxf(acc.w + bb.w, 0.f);
    *(float4*)&h1r[(size_t)wid * 256 + lane * 4] = o;
}

// ---------------- layer 2 (H=1) + fused mean-pool scatter ----------------

__global__ __launch_bounds__(256) void agg2_kernel(const int* __restrict__ rowstart,
                                                   const int* __restrict__ csr_src,
                                                   const float* __restrict__ csr_ea,
                                                   const float* __restrict__ asrc,
                                                   const float* __restrict__ adst,
                                                   const float* __restrict__ ws,
                                                   const float* __restrict__ h2pre,
                                                   const float* __restrict__ b2,
                                                   const int* __restrict__ bidx,
                                                   float* __restrict__ pool_s,
                                                   float* __restrict__ pool_cnt)
{
    int wid  = (blockIdx.x * blockDim.x + threadIdx.x) >> 6;
    int lane = threadIdx.x & 63;
    if (wid >= N_NODES) return;
    int rs = rowstart[wid], re = rowstart[wid + 1];
    float c2 = ws[6];
    float ad = adst[wid];
    float m = -1e30f, s = 0.f;
    for (int p = rs + lane; p < re; p += 64) {
        int src  = csr_src[p];
        float ev = csr_ea[p];
        float a  = asrc[src] + ad + ev * c2;
        a = a > 0.f ? a : 0.2f * a;
        float nm = fmaxf(m, a);
        s = s * __expf(m - nm) + __expf(a - nm);
        m = nm;
    }
    #pragma unroll
    for (int off = 1; off < 64; off <<= 1) {
        float om = __shfl_xor(m, off);
        float os = __shfl_xor(s, off);
        float nm = fmaxf(m, om);
        s = s * __expf(m - nm) + os * __expf(om - nm);
        m = nm;
    }
    float inv = 1.0f / (s + 1e-16f);

    float acc = 0.f;
    int p = rs;
    int nmain = rs + ((re - rs) & ~3);
    for (; p < nmain; p += 4) {
        int s0 = csr_src[p],     s1 = csr_src[p + 1];
        int s2 = csr_src[p + 2], s3 = csr_src[p + 3];
        float e0 = csr_ea[p],     e1 = csr_ea[p + 1];
        float e2 = csr_ea[p + 2], e3 = csr_ea[p + 3];
        float r0 = h2pre[(size_t)s0 * 64 + lane];
        float r1 = h2pre[(size_t)s1 * 64 + lane];
        float r2 = h2pre[(size_t)s2 * 64 + lane];
        float r3 = h2pre[(size_t)s3 * 64 + lane];
        float a0 = asrc[s0] + ad + e0 * c2; a0 = a0 > 0.f ? a0 : 0.2f * a0;
        float a1 = asrc[s1] + ad + e1 * c2; a1 = a1 > 0.f ? a1 : 0.2f * a1;
        float a2 = asrc[s2] + ad + e2 * c2; a2 = a2 > 0.f ? a2 : 0.2f * a2;
        float a3 = asrc[s3] + ad + e3 * c2; a3 = a3 > 0.f ? a3 : 0.2f * a3;
        float w0 = __expf(a0 - m) * inv;
        float w1 = __expf(a1 - m) * inv;
        float w2 = __expf(a2 - m) * inv;
        float w3 = __expf(a3 - m) * inv;
        acc = fmaf(r0, w0, fmaf(r1, w1, fmaf(r2, w2, fmaf(r3, w3, acc))));
    }
    for (; p < re; ++p) {
        int s0 = csr_src[p];
        float e0 = csr_ea[p];
        float r0 = h2pre[(size_t)s0 * 64 + lane];
        float a0 = asrc[s0] + ad + e0 * c2; a0 = a0 > 0.f ? a0 : 0.2f * a0;
        float w0 = __expf(a0 - m) * inv;
        acc = fmaf(r0, w0, acc);
    }
    float val = acc + b2[lane];
    int g = bidx[wid];
    atomicAdd(&pool_s[(size_t)g * 64 + lane], val);
    if (lane == 0) atomicAdd(&pool_cnt[g], 1.f);
}

// ---------------- MLP head: one wave per graph ----------------

__global__ __launch_bounds__(64) void mlp_kernel(const float* __restrict__ pool_s,
                                                 const float* __restrict__ pool_cnt,
                                                 const float* __restrict__ Wl1,
                                                 const float* __restrict__ bl1,
                                                 const float* __restrict__ lng,
                                                 const float* __restrict__ lnb,
                                                 const float* __restrict__ Wl2,
                                                 const float* __restrict__ bl2,
                                                 float* __restrict__ out)
{
    int g = blockIdx.x, l = threadIdx.x;
    __shared__ float gs[64], zs[64];
    float cnt = fmaxf(pool_cnt[g], 1.f);
    gs[l] = pool_s[(size_t)g * 64 + l] / cnt;
    __syncthreads();
    float z = bl1[l];
    for (int k = 0; k < 64; ++k) z = fmaf(gs[k], Wl1[k * 64 + l], z);
    z = fmaxf(z, 0.f);
    float sum = z;
    #pragma unroll
    for (int off = 32; off; off >>= 1) sum += __shfl_xor(sum, off);
    float mu = sum * (1.f / 64.f);
    float d  = z - mu;
    float vs = d * d;
    #pragma unroll
    for (int off = 32; off; off >>= 1) vs += __shfl_xor(vs, off);
    float var = vs * (1.f / 64.f);
    z = d * rsqrtf(var + 1e-5f) * lng[l] + lnb[l];
    zs[l] = z;
    __syncthreads();
    if (l < 16) {
        float o = bl2[l];
        for (int k = 0; k < 64; ++k) o = fmaf(zs[k], Wl2[k * 16 + l], o);
        out[g * 16 + l] = o;
    }
}

__global__ void copy_ea_kernel(const float* __restrict__ ea, float* __restrict__ out)
{
    for (int i = blockIdx.x * blockDim.x + threadIdx.x; i < N_EDGES; i += gridDim.x * blockDim.x)
        out[i] = ea[i];
}

// ---------------- launch ----------------

extern "C" void kernel_launch(void* const* d_in, const int* in_sizes, int n_in,
                              void* d_out, int out_size, void* d_ws, size_t ws_size,
                              hipStream_t stream)
{
    const float* x    = (const float*)d_in[0];
    const int*   ei   = (const int*)d_in[1];
    const float* ea   = (const float*)d_in[2];
    const int*   bidx = (const int*)d_in[3];
    const float* W1   = (const float*)d_in[4];
    const float* as1  = (const float*)d_in[5];
    const float* ad1  = (const float*)d_in[6];
    const float* We1  = (const float*)d_in[7];
    const float* ae1  = (const float*)d_in[8];
    const float* b1   = (const float*)d_in[9];
    const float* W2   = (const float*)d_in[10];
    const float* as2  = (const float*)d_in[11];
    const float* ad2  = (const float*)d_in[12];
    const float* We2  = (const float*)d_in[13];
    const float* ae2  = (const float*)d_in[14];
    const float* b2   = (const float*)d_in[15];
    const float* Wl1  = (const float*)d_in[16];
    const float* bl1  = (const float*)d_in[17];
    const float* lng  = (const float*)d_in[18];
    const float* lnb  = (const float*)d_in[19];
    const float* Wl2  = (const float*)d_in[20];
    const float* bl2  = (const float*)d_in[21];
    float* out = (float*)d_out;

    char* w = (char*)d_ws;
    float* scalars  = (float*)(w + 0);
    int*   deg      = (int*)  (w + 64);
    float* pool_s   = (float*)(w + 200064);
    float* pool_cnt = (float*)(w + 232832);
    const size_t zbytes = 233344;
    int*   rowstart = (int*)  (w + 233344);
    int*   cursor   = (int*)  (w + 433360);
    int*   csr_src  = (int*)  (w + 633360);
    float* csr_ea   = (float*)(w + 7233360);
    float* asrc1    = (float*)(w + 13833360);
    float* adst1    = (float*)(w + 14633360);
    float* asrc2    = (float*)(w + 15433360);
    float* adst2    = (float*)(w + 15633360);
    float* h1       = (float*)(w + 15833360);
    float* h1r      = (float*)(w + 67033360);
    float* h2pre    = (float*)(w + 118233360);

    hipMemsetAsync(d_ws, 0, zbytes, stream);
    ea_sum_kernel<<<512, 256, 0, stream>>>(ea, scalars, N_EDGES);
    scalars_kernel<<<1, 64, 0, stream>>>(scalars, We1, ae1, We2, ae2);
    deg_kernel<<<1024, 256, 0, stream>>>(ei, deg);
    scan_kernel<<<1, 1024, 0, stream>>>(deg, rowstart, cursor);
    fill_kernel<<<1024, 256, 0, stream>>>(ei, ea, scalars, cursor, csr_src, csr_ea);

    { dim3 g(4, 782);  gemm_tile<16><<<g, 256, 0, stream>>>(x,   W1, h1,    N_NODES, 128, 256); }
    alphas1_kernel<<<12500, 256, 0, stream>>>(h1, as1, ad1, asrc1, adst1);
    agg1_kernel<<<12500, 256, 0, stream>>>(rowstart, csr_src, csr_ea, asrc1, adst1,
                                           scalars, h1, b1, h1r);
    { dim3 g(1, 782);  gemm_tile<16><<<g, 256, 0, stream>>>(h1r, W2, h2pre, N_NODES, 256, 64); }
    alphas2_kernel<<<12500, 256, 0, stream>>>(h2pre, as2, ad2, asrc2, adst2);
    agg2_kernel<<<12500, 256, 0, stream>>>(rowstart, csr_src, csr_ea, asrc2, adst2,
                                           scalars, h2pre, b2, bidx, pool_s, pool_cnt);
    mlp_kernel<<<G_GRAPHS, 64, 0, stream>>>(pool_s, pool_cnt, Wl1, bl1, lng, lnb, Wl2, bl2, out);
    copy_ea_kernel<<<2048, 256, 0, stream>>>(ea, out + 2048);
}

// Round 3
// 1096.524 us; speedup vs baseline: 1.1115x; 1.0150x over previous
//
#include <hip/hip_runtime.h>
#include <hip/hip_bf16.h>

#define N_NODES 50000
#define N_EDGES 1600000
#define ET (N_EDGES + N_NODES)
#define G_GRAPHS 128

typedef unsigned short ushort8v __attribute__((ext_vector_type(8)));
typedef unsigned short ushort4v __attribute__((ext_vector_type(4)));

__device__ __forceinline__ float bf2f(unsigned short u)
{
    return __uint_as_float(((unsigned int)u) << 16);
}
__device__ __forceinline__ unsigned short f2bf(float f)
{
    unsigned int u = __float_as_uint(f);
    u = (u + 0x7FFFu + ((u >> 16) & 1u)) >> 16;
    return (unsigned short)u;
}

// ---------------- small utility kernels ----------------

__global__ void ea_sum_kernel(const float* __restrict__ ea, float* __restrict__ out, int n)
{
    float s = 0.f;
    for (int i = blockIdx.x * blockDim.x + threadIdx.x; i < n; i += gridDim.x * blockDim.x)
        s += ea[i];
    #pragma unroll
    for (int off = 32; off; off >>= 1) s += __shfl_xor(s, off);
    if ((threadIdx.x & 63) == 0) atomicAdd(out, s);
}

// ws scalars layout: [0]=ea_sum [1]=ea_mean [2..5]=c1[4] [6]=c2
__global__ void scalars_kernel(float* __restrict__ ws,
                               const float* __restrict__ We1, const float* __restrict__ ae1,
                               const float* __restrict__ We2, const float* __restrict__ ae2)
{
    if (threadIdx.x == 0 && blockIdx.x == 0) {
        ws[1] = ws[0] / (float)N_EDGES;
        for (int h = 0; h < 4; ++h) {
            float c = 0.f;
            for (int o = 0; o < 64; ++o) c += We1[h * 64 + o] * ae1[h * 64 + o];
            ws[2 + h] = c;
        }
        float c2 = 0.f;
        for (int o = 0; o < 64; ++o) c2 += We2[o] * ae2[o];
        ws[6] = c2;
    }
}

__global__ void deg_kernel(const int* __restrict__ ei, int* __restrict__ deg)
{
    for (int e = blockIdx.x * blockDim.x + threadIdx.x; e < ET; e += gridDim.x * blockDim.x) {
        int dst = (e < N_EDGES) ? ei[N_EDGES + e] : (e - N_EDGES);
        atomicAdd(&deg[dst], 1);
    }
}

__global__ __launch_bounds__(1024) void scan_kernel(const int* __restrict__ deg,
                                                    int* __restrict__ rowstart,
                                                    int* __restrict__ cursor)
{
    __shared__ int ssum[1024];
    const int C = (N_NODES + 1023) / 1024;   // 49
    int tid = threadIdx.x;
    int c0 = tid * C, c1 = min(c0 + C, N_NODES);
    int s = 0;
    for (int i = c0; i < c1; ++i) s += deg[i];
    ssum[tid] = s;
    __syncthreads();
    for (int off = 1; off < 1024; off <<= 1) {
        int v = (tid >= off) ? ssum[tid - off] : 0;
        __syncthreads();
        ssum[tid] += v;
        __syncthreads();
    }
    int run = ssum[tid] - s;  // exclusive prefix
    for (int i = c0; i < c1; ++i) { rowstart[i] = run; cursor[i] = run; run += deg[i]; }
    if (tid == 1023) rowstart[N_NODES] = ET;
}

__global__ void fill_kernel(const int* __restrict__ ei, const float* __restrict__ ea,
                            const float* __restrict__ ws, int* __restrict__ cursor,
                            int* __restrict__ csr_src, float* __restrict__ csr_ea)
{
    float mean = ws[1];
    for (int e = blockIdx.x * blockDim.x + threadIdx.x; e < ET; e += gridDim.x * blockDim.x) {
        int src, dst; float v;
        if (e < N_EDGES) { src = ei[e]; dst = ei[N_EDGES + e]; v = ea[e]; }
        else             { src = dst = e - N_EDGES; v = mean; }
        int pos = atomicAdd(&cursor[dst], 1);
        csr_src[pos] = src;
        csr_ea[pos]  = v;
    }
}

// ---------------- f32 tiled GEMM: C[M,NC] = A[M,K] @ B[K,NC] ----------------
// BM=BN=64, block 256 (16x16), 4x4 per thread, BK=16. Optional bf16 output.
template <int BK, bool BF16OUT>
__global__ __launch_bounds__(256) void gemm_tile(const float* __restrict__ A,
                                                 const float* __restrict__ B,
                                                 void* __restrict__ Cv,
                                                 int M, int K, int NC)
{
    __shared__ __align__(16) float As[BK][64];
    __shared__ __align__(16) float Bs[BK][64];
    int tid = threadIdx.x;
    int tx = tid & 15, ty = tid >> 4;
    int rowBase = blockIdx.y * 64;
    int colBase = blockIdx.x * 64;
    float acc[4][4] = {};
    for (int k0 = 0; k0 < K; k0 += BK) {
        {
            int r  = tid >> 2;
            int kq = (tid & 3) * 4;
            int grow = rowBase + r;
            float4 v = make_float4(0.f, 0.f, 0.f, 0.f);
            if (grow < M) v = *(const float4*)&A[(size_t)grow * K + k0 + kq];
            As[kq + 0][r] = v.x; As[kq + 1][r] = v.y;
            As[kq + 2][r] = v.z; As[kq + 3][r] = v.w;
        }
        {
            int kk = tid >> 4;
            int c  = (tid & 15) * 4;
            float4 v = *(const float4*)&B[(size_t)(k0 + kk) * NC + colBase + c];
            *(float4*)&Bs[kk][c] = v;
        }
        __syncthreads();
        #pragma unroll
        for (int k = 0; k < BK; ++k) {
            float4 a4 = *(const float4*)&As[k][ty * 4];
            float4 b4 = *(const float4*)&Bs[k][tx * 4];
            float aa[4] = {a4.x, a4.y, a4.z, a4.w};
            float bb[4] = {b4.x, b4.y, b4.z, b4.w};
            #pragma unroll
            for (int i = 0; i < 4; ++i)
                #pragma unroll
                for (int j = 0; j < 4; ++j)
                    acc[i][j] = fmaf(aa[i], bb[j], acc[i][j]);
        }
        __syncthreads();
    }
    #pragma unroll
    for (int i = 0; i < 4; ++i) {
        int grow = rowBase + ty * 4 + i;
        if (grow < M) {
            if constexpr (BF16OUT) {
                ushort4v o;
                o[0] = f2bf(acc[i][0]); o[1] = f2bf(acc[i][1]);
                o[2] = f2bf(acc[i][2]); o[3] = f2bf(acc[i][3]);
                *(ushort4v*)&((unsigned short*)Cv)[(size_t)grow * NC + colBase + tx * 4] = o;
            } else {
                float4 o = make_float4(acc[i][0], acc[i][1], acc[i][2], acc[i][3]);
                *(float4*)&((float*)Cv)[(size_t)grow * NC + colBase + tx * 4] = o;
            }
        }
    }
}

// ---------------- per-node alpha projections (bf16 features) ----------------

__global__ __launch_bounds__(256) void alphas1_kernel(const unsigned short* __restrict__ h1bf,
                                                      const float* __restrict__ as1,
                                                      const float* __restrict__ ad1,
                                                      float* __restrict__ asrc,
                                                      float* __restrict__ adst)
{
    int wid  = (blockIdx.x * blockDim.x + threadIdx.x) >> 6;
    int lane = threadIdx.x & 63;
    if (wid >= N_NODES) return;
    const unsigned short* hr = h1bf + (size_t)wid * 256;
    float sa[4], da[4];
    #pragma unroll
    for (int j = 0; j < 4; ++j) {
        float v = bf2f(hr[j * 64 + lane]);
        sa[j] = v * as1[j * 64 + lane];
        da[j] = v * ad1[j * 64 + lane];
    }
    #pragma unroll
    for (int off = 32; off; off >>= 1)
        #pragma unroll
        for (int j = 0; j < 4; ++j) {
            sa[j] += __shfl_xor(sa[j], off);
            da[j] += __shfl_xor(da[j], off);
        }
    if (lane == 0)
        #pragma unroll
        for (int j = 0; j < 4; ++j) {
            asrc[(size_t)wid * 4 + j] = sa[j];
            adst[(size_t)wid * 4 + j] = da[j];
        }
}

__global__ __launch_bounds__(256) void alphas2_kernel(const unsigned short* __restrict__ h2bf,
                                                      const float* __restrict__ as2,
                                                      const float* __restrict__ ad2,
                                                      float* __restrict__ asrc,
                                                      float* __restrict__ adst)
{
    int wid  = (blockIdx.x * blockDim.x + threadIdx.x) >> 6;
    int lane = threadIdx.x & 63;
    if (wid >= N_NODES) return;
    float v  = bf2f(h2bf[(size_t)wid * 64 + lane]);
    float sa = v * as2[lane];
    float da = v * ad2[lane];
    #pragma unroll
    for (int off = 32; off; off >>= 1) {
        sa += __shfl_xor(sa, off);
        da += __shfl_xor(da, off);
    }
    if (lane == 0) { asrc[wid] = sa; adst[wid] = da; }
}

// ---------------- layer 1: softmax + aggregation, one wave per dst node ----------------
// phase 2: 2 lane-groups x 32 lanes; lane covers 8 channels; 4 loads = 8 edges/iter.

__global__ __launch_bounds__(256) void agg1_kernel(const int* __restrict__ rowstart,
                                                   const int* __restrict__ csr_src,
                                                   const float* __restrict__ csr_ea,
                                                   const float* __restrict__ asrc,
                                                   const float* __restrict__ adst,
                                                   const float* __restrict__ ws,
                                                   const unsigned short* __restrict__ h1bf,
                                                   const float* __restrict__ b1,
                                                   float* __restrict__ h1r)
{
    int wid  = (blockIdx.x * blockDim.x + threadIdx.x) >> 6;
    int lane = threadIdx.x & 63;
    if (wid >= N_NODES) return;
    int rs = rowstart[wid], re = rowstart[wid + 1];
    float c[4], ad[4];
    #pragma unroll
    for (int h = 0; h < 4; ++h) { c[h] = ws[2 + h]; ad[h] = adst[(size_t)wid * 4 + h]; }

    // phase 1: online max+sum per head, edges strided across lanes
    float m[4] = {-1e30f, -1e30f, -1e30f, -1e30f}, s[4] = {0.f, 0.f, 0.f, 0.f};
    for (int p = rs + lane; p < re; p += 64) {
        int src  = csr_src[p];
        float ev = csr_ea[p];
        float4 av = *(const float4*)&asrc[(size_t)src * 4];
        float a[4] = {av.x + ad[0] + ev * c[0], av.y + ad[1] + ev * c[1],
                      av.z + ad[2] + ev * c[2], av.w + ad[3] + ev * c[3]};
        #pragma unroll
        for (int h = 0; h < 4; ++h) {
            float x  = a[h] > 0.f ? a[h] : 0.2f * a[h];
            float nm = fmaxf(m[h], x);
            s[h] = s[h] * __expf(m[h] - nm) + __expf(x - nm);
            m[h] = nm;
        }
    }
    #pragma unroll
    for (int off = 1; off < 64; off <<= 1)
        #pragma unroll
        for (int h = 0; h < 4; ++h) {
            float om = __shfl_xor(m[h], off);
            float os = __shfl_xor(s[h], off);
            float nm = fmaxf(m[h], om);
            s[h] = s[h] * __expf(m[h] - nm) + os * __expf(om - nm);
            m[h] = nm;
        }
    float inv[4];
    #pragma unroll
    for (int h = 0; h < 4; ++h) inv[h] = 1.0f / (s[h] + 1e-16f);

    // phase 2
    int g   = lane >> 5;        // edge sub-slot (0..1)
    int sub = lane & 31;        // channel block: channels sub*8 .. sub*8+7
    int hh  = sub >> 3;         // head of this lane's channels
    float ad_s = hh < 2 ? (hh == 0 ? ad[0] : ad[1]) : (hh == 2 ? ad[2] : ad[3]);
    float c_s  = hh < 2 ? (hh == 0 ? c[0]  : c[1])  : (hh == 2 ? c[2]  : c[3]);
    float m_s  = hh < 2 ? (hh == 0 ? m[0]  : m[1])  : (hh == 2 ? m[2]  : m[3]);
    float i_s  = hh < 2 ? (hh == 0 ? inv[0]: inv[1]): (hh == 2 ? inv[2]: inv[3]);

    float acc[8] = {};
    for (int p = rs; p < re; p += 8) {
        #pragma unroll
        for (int k = 0; k < 4; ++k) {
            int pe = p + 2 * k + g;
            bool act = pe < re;
            int idx = act ? pe : re - 1;
            int src  = csr_src[idx];
            float ev = csr_ea[idx];
            ushort8v r = *(const ushort8v*)&h1bf[(size_t)src * 256 + sub * 8];
            float al = asrc[(size_t)src * 4 + hh] + ad_s + ev * c_s;
            al = al > 0.f ? al : 0.2f * al;
            float wgt = act ? __expf(al - m_s) * i_s : 0.f;
            #pragma unroll
            for (int j = 0; j < 8; ++j)
                acc[j] = fmaf(bf2f(r[j]), wgt, acc[j]);
        }
    }
    #pragma unroll
    for (int j = 0; j < 8; ++j) acc[j] += __shfl_xor(acc[j], 32);
    if (g == 0) {
        float* o = h1r + (size_t)wid * 256 + sub * 8;
        float4 ba = *(const float4*)&b1[sub * 8];
        float4 bb = *(const float4*)&b1[sub * 8 + 4];
        float4 o0, o1;
        o0.x = fmaxf(acc[0] + ba.x, 0.f); o0.y = fmaxf(acc[1] + ba.y, 0.f);
        o0.z = fmaxf(acc[2] + ba.z, 0.f); o0.w = fmaxf(acc[3] + ba.w, 0.f);
        o1.x = fmaxf(acc[4] + bb.x, 0.f); o1.y = fmaxf(acc[5] + bb.y, 0.f);
        o1.z = fmaxf(acc[6] + bb.z, 0.f); o1.w = fmaxf(acc[7] + bb.w, 0.f);
        *(float4*)&o[0] = o0;
        *(float4*)&o[4] = o1;
    }
}

// ---------------- layer 2 (H=1) + fused mean-pool scatter ----------------
// phase 2: 8 lane-groups x 8 lanes; lane covers 8 channels; 2 loads = 16 edges/iter.

__global__ __launch_bounds__(256) void agg2_kernel(const int* __restrict__ rowstart,
                                                   const int* __restrict__ csr_src,
                                                   const float* __restrict__ csr_ea,
                                                   const float* __restrict__ asrc,
                                                   const float* __restrict__ adst,
                                                   const float* __restrict__ ws,
                                                   const unsigned short* __restrict__ h2bf,
                                                   const float* __restrict__ b2,
                                                   const int* __restrict__ bidx,
                                                   float* __restrict__ pool_s,
                                                   float* __restrict__ pool_cnt)
{
    __shared__ float sh[4][64];
    int wid  = (blockIdx.x * blockDim.x + threadIdx.x) >> 6;
    int lane = threadIdx.x & 63;
    if (wid >= N_NODES) return;   // never taken: grid == N_NODES waves exactly
    int rs = rowstart[wid], re = rowstart[wid + 1];
    float c2 = ws[6];
    float ad = adst[wid];
    float m = -1e30f, s = 0.f;
    for (int p = rs + lane; p < re; p += 64) {
        int src  = csr_src[p];
        float ev = csr_ea[p];
        float a  = asrc[src] + ad + ev * c2;
        a = a > 0.f ? a : 0.2f * a;
        float nm = fmaxf(m, a);
        s = s * __expf(m - nm) + __expf(a - nm);
        m = nm;
    }
    #pragma unroll
    for (int off = 1; off < 64; off <<= 1) {
        float om = __shfl_xor(m, off);
        float os = __shfl_xor(s, off);
        float nm = fmaxf(m, om);
        s = s * __expf(m - nm) + os * __expf(om - nm);
        m = nm;
    }
    float inv = 1.0f / (s + 1e-16f);

    int g   = lane >> 3;   // edge sub-slot (0..7)
    int sub = lane & 7;    // channel block: channels sub*8 .. sub*8+7
    float acc[8] = {};
    for (int p = rs; p < re; p += 16) {
        #pragma unroll
        for (int k = 0; k < 2; ++k) {
            int pe = p + 8 * k + g;
            bool act = pe < re;
            int idx = act ? pe : re - 1;
            int src  = csr_src[idx];
            float ev = csr_ea[idx];
            ushort8v r = *(const ushort8v*)&h2bf[(size_t)src * 64 + sub * 8];
            float al = asrc[src] + ad + ev * c2;
            al = al > 0.f ? al : 0.2f * al;
            float wgt = act ? __expf(al - m) * inv : 0.f;
            #pragma unroll
            for (int j = 0; j < 8; ++j)
                acc[j] = fmaf(bf2f(r[j]), wgt, acc[j]);
        }
    }
    #pragma unroll
    for (int j = 0; j < 8; ++j) {
        acc[j] += __shfl_xor(acc[j], 8);
        acc[j] += __shfl_xor(acc[j], 16);
        acc[j] += __shfl_xor(acc[j], 32);
    }
    int wv = threadIdx.x >> 6;
    if (g == 0) {
        #pragma unroll
        for (int j = 0; j < 8; ++j) sh[wv][sub * 8 + j] = acc[j];
    }
    __syncthreads();
    float val = sh[wv][lane] + b2[lane];
    int gg = bidx[wid];
    atomicAdd(&pool_s[(size_t)gg * 64 + lane], val);
    if (lane == 0) atomicAdd(&pool_cnt[gg], 1.f);
}

// ---------------- MLP head: one wave per graph ----------------

__global__ __launch_bounds__(64) void mlp_kernel(const float* __restrict__ pool_s,
                                                 const float* __restrict__ pool_cnt,
                                                 const float* __restrict__ Wl1,
                                                 const float* __restrict__ bl1,
                                                 const float* __restrict__ lng,
                                                 const float* __restrict__ lnb,
                                                 const float* __restrict__ Wl2,
                                                 const float* __restrict__ bl2,
                                                 float* __restrict__ out)
{
    int g = blockIdx.x, l = threadIdx.x;
    __shared__ float gs[64], zs[64];
    float cnt = fmaxf(pool_cnt[g], 1.f);
    gs[l] = pool_s[(size_t)g * 64 + l] / cnt;
    __syncthreads();
    float z = bl1[l];
    for (int k = 0; k < 64; ++k) z = fmaf(gs[k], Wl1[k * 64 + l], z);
    z = fmaxf(z, 0.f);
    float sum = z;
    #pragma unroll
    for (int off = 32; off; off >>= 1) sum += __shfl_xor(sum, off);
    float mu = sum * (1.f / 64.f);
    float d  = z - mu;
    float vs = d * d;
    #pragma unroll
    for (int off = 32; off; off >>= 1) vs += __shfl_xor(vs, off);
    float var = vs * (1.f / 64.f);
    z = d * rsqrtf(var + 1e-5f) * lng[l] + lnb[l];
    zs[l] = z;
    __syncthreads();
    if (l < 16) {
        float o = bl2[l];
        for (int k = 0; k < 64; ++k) o = fmaf(zs[k], Wl2[k * 16 + l], o);
        out[g * 16 + l] = o;
    }
}

__global__ void copy_ea_kernel(const float* __restrict__ ea, float* __restrict__ out)
{
    for (int i = blockIdx.x * blockDim.x + threadIdx.x; i < N_EDGES; i += gridDim.x * blockDim.x)
        out[i] = ea[i];
}

// ---------------- launch ----------------

extern "C" void kernel_launch(void* const* d_in, const int* in_sizes, int n_in,
                              void* d_out, int out_size, void* d_ws, size_t ws_size,
                              hipStream_t stream)
{
    const float* x    = (const float*)d_in[0];
    const int*   ei   = (const int*)d_in[1];
    const float* ea   = (const float*)d_in[2];
    const int*   bidx = (const int*)d_in[3];
    const float* W1   = (const float*)d_in[4];
    const float* as1  = (const float*)d_in[5];
    const float* ad1  = (const float*)d_in[6];
    const float* We1  = (const float*)d_in[7];
    const float* ae1  = (const float*)d_in[8];
    const float* b1   = (const float*)d_in[9];
    const float* W2   = (const float*)d_in[10];
    const float* as2  = (const float*)d_in[11];
    const float* ad2  = (const float*)d_in[12];
    const float* We2  = (const float*)d_in[13];
    const float* ae2  = (const float*)d_in[14];
    const float* b2   = (const float*)d_in[15];
    const float* Wl1  = (const float*)d_in[16];
    const float* bl1  = (const float*)d_in[17];
    const float* lng  = (const float*)d_in[18];
    const float* lnb  = (const float*)d_in[19];
    const float* Wl2  = (const float*)d_in[20];
    const float* bl2  = (const float*)d_in[21];
    float* out = (float*)d_out;

    char* w = (char*)d_ws;
    float* scalars  = (float*)(w + 0);
    int*   deg      = (int*)  (w + 64);
    float* pool_s   = (float*)(w + 200064);
    float* pool_cnt = (float*)(w + 232832);
    const size_t zbytes = 233344;
    int*   rowstart = (int*)  (w + 233344);
    int*   cursor   = (int*)  (w + 433360);
    int*   csr_src  = (int*)  (w + 633360);
    float* csr_ea   = (float*)(w + 7233360);
    float* asrc1    = (float*)(w + 13833360);
    float* adst1    = (float*)(w + 14633360);
    float* asrc2    = (float*)(w + 15433360);
    float* adst2    = (float*)(w + 15633360);
    unsigned short* h1bf = (unsigned short*)(w + 15833360);   // 25.6 MB
    float* h1r      = (float*)(w + 41433360);                  // 51.2 MB
    unsigned short* h2bf = (unsigned short*)(w + 92633360);   // 6.4 MB

    hipMemsetAsync(d_ws, 0, zbytes, stream);
    ea_sum_kernel<<<512, 256, 0, stream>>>(ea, scalars, N_EDGES);
    scalars_kernel<<<1, 64, 0, stream>>>(scalars, We1, ae1, We2, ae2);
    deg_kernel<<<1024, 256, 0, stream>>>(ei, deg);
    scan_kernel<<<1, 1024, 0, stream>>>(deg, rowstart, cursor);
    fill_kernel<<<1024, 256, 0, stream>>>(ei, ea, scalars, cursor, csr_src, csr_ea);

    { dim3 g(4, 782);  gemm_tile<16, true><<<g, 256, 0, stream>>>(x, W1, h1bf, N_NODES, 128, 256); }
    alphas1_kernel<<<12500, 256, 0, stream>>>(h1bf, as1, ad1, asrc1, adst1);
    agg1_kernel<<<12500, 256, 0, stream>>>(rowstart, csr_src, csr_ea, asrc1, adst1,
                                           scalars, h1bf, b1, h1r);
    { dim3 g(1, 782);  gemm_tile<16, true><<<g, 256, 0, stream>>>(h1r, W2, h2bf, N_NODES, 256, 64); }
    alphas2_kernel<<<12500, 256, 0, stream>>>(h2bf, as2, ad2, asrc2, adst2);
    agg2_kernel<<<12500, 256, 0, stream>>>(rowstart, csr_src, csr_ea, asrc2, adst2,
                                           scalars, h2bf, b2, bidx, pool_s, pool_cnt);
    mlp_kernel<<<G_GRAPHS, 64, 0, stream>>>(pool_s, pool_cnt, Wl1, bl1, lng, lnb, Wl2, bl2, out);
    copy_ea_kernel<<<2048, 256, 0, stream>>>(ea, out + 2048);
}

// Round 5
// 794.878 us; speedup vs baseline: 1.5332x; 1.3795x over previous
//
#include <hip/hip_runtime.h>
#include <hip/hip_bf16.h>

#define N_NODES 50000
#define N_EDGES 1600000
#define ET (N_EDGES + N_NODES)
#define G_GRAPHS 128

typedef unsigned short ushort8v __attribute__((ext_vector_type(8)));
typedef unsigned short ushort4v __attribute__((ext_vector_type(4)));

__device__ __forceinline__ float bf2f(unsigned short u)
{
    return __uint_as_float(((unsigned int)u) << 16);
}
__device__ __forceinline__ unsigned short f2bf(float f)
{
    unsigned int u = __float_as_uint(f);
    u = (u + 0x7FFFu + ((u >> 16) & 1u)) >> 16;
    return (unsigned short)u;
}

// ---------------- small utility kernels ----------------

__global__ void ea_sum_kernel(const float* __restrict__ ea, float* __restrict__ out, int n)
{
    float s = 0.f;
    for (int i = blockIdx.x * blockDim.x + threadIdx.x; i < n; i += gridDim.x * blockDim.x)
        s += ea[i];
    #pragma unroll
    for (int off = 32; off; off >>= 1) s += __shfl_xor(s, off);
    if ((threadIdx.x & 63) == 0) atomicAdd(out, s);
}

// ws scalars layout: [0]=ea_sum [1]=ea_mean [2..5]=c1[4] [6]=c2
__global__ void scalars_kernel(float* __restrict__ ws,
                               const float* __restrict__ We1, const float* __restrict__ ae1,
                               const float* __restrict__ We2, const float* __restrict__ ae2)
{
    if (threadIdx.x == 0 && blockIdx.x == 0) {
        ws[1] = ws[0] / (float)N_EDGES;
        for (int h = 0; h < 4; ++h) {
            float c = 0.f;
            for (int o = 0; o < 64; ++o) c += We1[h * 64 + o] * ae1[h * 64 + o];
            ws[2 + h] = c;
        }
        float c2 = 0.f;
        for (int o = 0; o < 64; ++o) c2 += We2[o] * ae2[o];
        ws[6] = c2;
    }
}

__global__ void deg_kernel(const int* __restrict__ ei, int* __restrict__ deg)
{
    for (int e = blockIdx.x * blockDim.x + threadIdx.x; e < ET; e += gridDim.x * blockDim.x) {
        int dst = (e < N_EDGES) ? ei[N_EDGES + e] : (e - N_EDGES);
        atomicAdd(&deg[dst], 1);
    }
}

__global__ __launch_bounds__(1024) void scan_kernel(const int* __restrict__ deg,
                                                    int* __restrict__ rowstart,
                                                    int* __restrict__ cursor)
{
    __shared__ int ssum[1024];
    const int C = (N_NODES + 1023) / 1024;   // 49
    int tid = threadIdx.x;
    int c0 = tid * C, c1 = min(c0 + C, N_NODES);
    int s = 0;
    for (int i = c0; i < c1; ++i) s += deg[i];
    ssum[tid] = s;
    __syncthreads();
    for (int off = 1; off < 1024; off <<= 1) {
        int v = (tid >= off) ? ssum[tid - off] : 0;
        __syncthreads();
        ssum[tid] += v;
        __syncthreads();
    }
    int run = ssum[tid] - s;  // exclusive prefix
    for (int i = c0; i < c1; ++i) { rowstart[i] = run; cursor[i] = run; run += deg[i]; }
    if (tid == 1023) rowstart[N_NODES] = ET;
}

__global__ void fill_kernel(const int* __restrict__ ei, const float* __restrict__ ea,
                            const float* __restrict__ ws, int* __restrict__ cursor,
                            int* __restrict__ csr_src, float* __restrict__ csr_ea)
{
    float mean = ws[1];
    for (int e = blockIdx.x * blockDim.x + threadIdx.x; e < ET; e += gridDim.x * blockDim.x) {
        int src, dst; float v;
        if (e < N_EDGES) { src = ei[e]; dst = ei[N_EDGES + e]; v = ea[e]; }
        else             { src = dst = e - N_EDGES; v = mean; }
        int pos = atomicAdd(&cursor[dst], 1);
        csr_src[pos] = src;
        csr_ea[pos]  = v;
    }
}

// graph start offsets in the sorted batch_idx (129 entries)
__global__ void gstart_kernel(const int* __restrict__ bidx, int* __restrict__ gstart)
{
    int g = blockIdx.x * blockDim.x + threadIdx.x;
    if (g > G_GRAPHS) return;
    int lo = 0, hi = N_NODES;
    while (lo < hi) { int mid = (lo + hi) >> 1; if (bidx[mid] < g) lo = mid + 1; else hi = mid; }
    gstart[g] = lo;
}

// ---------------- f32 tiled GEMM: C[M,NC] = A[M,K] @ B[K,NC] ----------------
template <int BK, bool BF16OUT>
__global__ __launch_bounds__(256) void gemm_tile(const float* __restrict__ A,
                                                 const float* __restrict__ B,
                                                 void* __restrict__ Cv,
                                                 int M, int K, int NC)
{
    __shared__ __align__(16) float As[BK][64];
    __shared__ __align__(16) float Bs[BK][64];
    int tid = threadIdx.x;
    int tx = tid & 15, ty = tid >> 4;
    int rowBase = blockIdx.y * 64;
    int colBase = blockIdx.x * 64;
    float acc[4][4] = {};
    for (int k0 = 0; k0 < K; k0 += BK) {
        {
            int r  = tid >> 2;
            int kq = (tid & 3) * 4;
            int grow = rowBase + r;
            float4 v = make_float4(0.f, 0.f, 0.f, 0.f);
            if (grow < M) v = *(const float4*)&A[(size_t)grow * K + k0 + kq];
            As[kq + 0][r] = v.x; As[kq + 1][r] = v.y;
            As[kq + 2][r] = v.z; As[kq + 3][r] = v.w;
        }
        {
            int kk = tid >> 4;
            int c  = (tid & 15) * 4;
            float4 v = *(const float4*)&B[(size_t)(k0 + kk) * NC + colBase + c];
            *(float4*)&Bs[kk][c] = v;
        }
        __syncthreads();
        #pragma unroll
        for (int k = 0; k < BK; ++k) {
            float4 a4 = *(const float4*)&As[k][ty * 4];
            float4 b4 = *(const float4*)&Bs[k][tx * 4];
            float aa[4] = {a4.x, a4.y, a4.z, a4.w};
            float bb[4] = {b4.x, b4.y, b4.z, b4.w};
            #pragma unroll
            for (int i = 0; i < 4; ++i)
                #pragma unroll
                for (int j = 0; j < 4; ++j)
                    acc[i][j] = fmaf(aa[i], bb[j], acc[i][j]);
        }
        __syncthreads();
    }
    #pragma unroll
    for (int i = 0; i < 4; ++i) {
        int grow = rowBase + ty * 4 + i;
        if (grow < M) {
            if constexpr (BF16OUT) {
                ushort4v o;
                o[0] = f2bf(acc[i][0]); o[1] = f2bf(acc[i][1]);
                o[2] = f2bf(acc[i][2]); o[3] = f2bf(acc[i][3]);
                *(ushort4v*)&((unsigned short*)Cv)[(size_t)grow * NC + colBase + tx * 4] = o;
            } else {
                float4 o = make_float4(acc[i][0], acc[i][1], acc[i][2], acc[i][3]);
                *(float4*)&((float*)Cv)[(size_t)grow * NC + colBase + tx * 4] = o;
            }
        }
    }
}

// ---------------- per-node alpha projections (bf16 features) ----------------

__global__ __launch_bounds__(256) void alphas1_kernel(const unsigned short* __restrict__ h1bf,
                                                      const float* __restrict__ as1,
                                                      const float* __restrict__ ad1,
                                                      float* __restrict__ asrc,
                                                      float* __restrict__ adst)
{
    int wid  = (blockIdx.x * blockDim.x + threadIdx.x) >> 6;
    int lane = threadIdx.x & 63;
    if (wid >= N_NODES) return;
    const unsigned short* hr = h1bf + (size_t)wid * 256;
    float sa[4], da[4];
    #pragma unroll
    for (int j = 0; j < 4; ++j) {
        float v = bf2f(hr[j * 64 + lane]);
        sa[j] = v * as1[j * 64 + lane];
        da[j] = v * ad1[j * 64 + lane];
    }
    #pragma unroll
    for (int off = 32; off; off >>= 1)
        #pragma unroll
        for (int j = 0; j < 4; ++j) {
            sa[j] += __shfl_xor(sa[j], off);
            da[j] += __shfl_xor(da[j], off);
        }
    if (lane == 0)
        #pragma unroll
        for (int j = 0; j < 4; ++j) {
            asrc[(size_t)wid * 4 + j] = sa[j];
            adst[(size_t)wid * 4 + j] = da[j];
        }
}

__global__ __launch_bounds__(256) void alphas2_kernel(const unsigned short* __restrict__ h2bf,
                                                      const float* __restrict__ as2,
                                                      const float* __restrict__ ad2,
                                                      float* __restrict__ asrc,
                                                      float* __restrict__ adst)
{
    int wid  = (blockIdx.x * blockDim.x + threadIdx.x) >> 6;
    int lane = threadIdx.x & 63;
    if (wid >= N_NODES) return;
    float v  = bf2f(h2bf[(size_t)wid * 64 + lane]);
    float sa = v * as2[lane];
    float da = v * ad2[lane];
    #pragma unroll
    for (int off = 32; off; off >>= 1) {
        sa += __shfl_xor(sa, off);
        da += __shfl_xor(da, off);
    }
    if (lane == 0) { asrc[wid] = sa; adst[wid] = da; }
}

// ---------------- layer 1: softmax + aggregation, one wave per dst node ----------------
// phase 2: 2 lane-groups x 32 lanes; lane covers 8 channels; 8 loads = 16 edges/iter.

__global__ __launch_bounds__(256) void agg1_kernel(const int* __restrict__ rowstart,
                                                   const int* __restrict__ csr_src,
                                                   const float* __restrict__ csr_ea,
                                                   const float* __restrict__ asrc,
                                                   const float* __restrict__ adst,
                                                   const float* __restrict__ ws,
                                                   const unsigned short* __restrict__ h1bf,
                                                   const float* __restrict__ b1,
                                                   float* __restrict__ h1r)
{
    int wid  = (blockIdx.x * blockDim.x + threadIdx.x) >> 6;
    int lane = threadIdx.x & 63;
    if (wid >= N_NODES) return;
    int rs = rowstart[wid], re = rowstart[wid + 1];
    float c[4], ad[4];
    #pragma unroll
    for (int h = 0; h < 4; ++h) { c[h] = ws[2 + h]; ad[h] = adst[(size_t)wid * 4 + h]; }

    // phase 1: online max+sum per head, edges strided across lanes
    float m[4] = {-1e30f, -1e30f, -1e30f, -1e30f}, s[4] = {0.f, 0.f, 0.f, 0.f};
    for (int p = rs + lane; p < re; p += 64) {
        int src  = csr_src[p];
        float ev = csr_ea[p];
        float4 av = *(const float4*)&asrc[(size_t)src * 4];
        float a[4] = {av.x + ad[0] + ev * c[0], av.y + ad[1] + ev * c[1],
                      av.z + ad[2] + ev * c[2], av.w + ad[3] + ev * c[3]};
        #pragma unroll
        for (int h = 0; h < 4; ++h) {
            float x  = a[h] > 0.f ? a[h] : 0.2f * a[h];
            float nm = fmaxf(m[h], x);
            s[h] = s[h] * __expf(m[h] - nm) + __expf(x - nm);
            m[h] = nm;
        }
    }
    #pragma unroll
    for (int off = 1; off < 64; off <<= 1)
        #pragma unroll
        for (int h = 0; h < 4; ++h) {
            float om = __shfl_xor(m[h], off);
            float os = __shfl_xor(s[h], off);
            float nm = fmaxf(m[h], om);
            s[h] = s[h] * __expf(m[h] - nm) + os * __expf(om - nm);
            m[h] = nm;
        }
    float inv[4];
    #pragma unroll
    for (int h = 0; h < 4; ++h) inv[h] = 1.0f / (s[h] + 1e-16f);

    // phase 2
    int g   = lane >> 5;        // edge sub-slot (0..1)
    int sub = lane & 31;        // channel block: channels sub*8 .. sub*8+7
    int hh  = sub >> 3;         // head of this lane's channels
    float ad_s = hh < 2 ? (hh == 0 ? ad[0] : ad[1]) : (hh == 2 ? ad[2] : ad[3]);
    float c_s  = hh < 2 ? (hh == 0 ? c[0]  : c[1])  : (hh == 2 ? c[2]  : c[3]);
    float m_s  = hh < 2 ? (hh == 0 ? m[0]  : m[1])  : (hh == 2 ? m[2]  : m[3]);
    float i_s  = hh < 2 ? (hh == 0 ? inv[0]: inv[1]): (hh == 2 ? inv[2]: inv[3]);

    float acc[8] = {};
    for (int p = rs; p < re; p += 16) {
        #pragma unroll
        for (int k = 0; k < 8; ++k) {
            int pe = p + 2 * k + g;
            bool act = pe < re;
            int idx = act ? pe : re - 1;
            int src  = csr_src[idx];
            float ev = csr_ea[idx];
            ushort8v r = *(const ushort8v*)&h1bf[(size_t)src * 256 + sub * 8];
            float al = asrc[(size_t)src * 4 + hh] + ad_s + ev * c_s;
            al = al > 0.f ? al : 0.2f * al;
            float wgt = act ? __expf(al - m_s) * i_s : 0.f;
            #pragma unroll
            for (int j = 0; j < 8; ++j)
                acc[j] = fmaf(bf2f(r[j]), wgt, acc[j]);
        }
    }
    #pragma unroll
    for (int j = 0; j < 8; ++j) acc[j] += __shfl_xor(acc[j], 32);
    if (g == 0) {
        float* o = h1r + (size_t)wid * 256 + sub * 8;
        float4 ba = *(const float4*)&b1[sub * 8];
        float4 bb = *(const float4*)&b1[sub * 8 + 4];
        float4 o0, o1;
        o0.x = fmaxf(acc[0] + ba.x, 0.f); o0.y = fmaxf(acc[1] + ba.y, 0.f);
        o0.z = fmaxf(acc[2] + ba.z, 0.f); o0.w = fmaxf(acc[3] + ba.w, 0.f);
        o1.x = fmaxf(acc[4] + bb.x, 0.f); o1.y = fmaxf(acc[5] + bb.y, 0.f);
        o1.z = fmaxf(acc[6] + bb.z, 0.f); o1.w = fmaxf(acc[7] + bb.w, 0.f);
        *(float4*)&o[0] = o0;
        *(float4*)&o[4] = o1;
    }
}

// ---------------- layer 2 (H=1): softmax + aggregation, direct store (no atomics) ----------------
// phase 2: 8 lane-groups x 8 lanes; lane covers 8 channels; 4 loads = 32 edges/iter.

__global__ __launch_bounds__(256) void agg2_kernel(const int* __restrict__ rowstart,
                                                   const int* __restrict__ csr_src,
                                                   const float* __restrict__ csr_ea,
                                                   const float* __restrict__ asrc,
                                                   const float* __restrict__ adst,
                                                   const float* __restrict__ ws,
                                                   const unsigned short* __restrict__ h2bf,
                                                   const float* __restrict__ b2,
                                                   float* __restrict__ h2out)
{
    int wid  = (blockIdx.x * blockDim.x + threadIdx.x) >> 6;
    int lane = threadIdx.x & 63;
    if (wid >= N_NODES) return;
    int rs = rowstart[wid], re = rowstart[wid + 1];
    float c2 = ws[6];
    float ad = adst[wid];
    float m = -1e30f, s = 0.f;
    for (int p = rs + lane; p < re; p += 64) {
        int src  = csr_src[p];
        float ev = csr_ea[p];
        float a  = asrc[src] + ad + ev * c2;
        a = a > 0.f ? a : 0.2f * a;
        float nm = fmaxf(m, a);
        s = s * __expf(m - nm) + __expf(a - nm);
        m = nm;
    }
    #pragma unroll
    for (int off = 1; off < 64; off <<= 1) {
        float om = __shfl_xor(m, off);
        float os = __shfl_xor(s, off);
        float nm = fmaxf(m, om);
        s = s * __expf(m - nm) + os * __expf(om - nm);
        m = nm;
    }
    float inv = 1.0f / (s + 1e-16f);

    int g   = lane >> 3;   // edge sub-slot (0..7)
    int sub = lane & 7;    // channel block: channels sub*8 .. sub*8+7
    float acc[8] = {};
    for (int p = rs; p < re; p += 32) {
        #pragma unroll
        for (int k = 0; k < 4; ++k) {
            int pe = p + 8 * k + g;
            bool act = pe < re;
            int idx = act ? pe : re - 1;
            int src  = csr_src[idx];
            float ev = csr_ea[idx];
            ushort8v r = *(const ushort8v*)&h2bf[(size_t)src * 64 + sub * 8];
            float al = asrc[src] + ad + ev * c2;
            al = al > 0.f ? al : 0.2f * al;
            float wgt = act ? __expf(al - m) * inv : 0.f;
            #pragma unroll
            for (int j = 0; j < 8; ++j)
                acc[j] = fmaf(bf2f(r[j]), wgt, acc[j]);
        }
    }
    #pragma unroll
    for (int j = 0; j < 8; ++j) {
        acc[j] += __shfl_xor(acc[j], 8);
        acc[j] += __shfl_xor(acc[j], 16);
        acc[j] += __shfl_xor(acc[j], 32);
    }
    if (g == 0) {
        float4 ba = *(const float4*)&b2[sub * 8];
        float4 bb = *(const float4*)&b2[sub * 8 + 4];
        float4 o0, o1;
        o0.x = acc[0] + ba.x; o0.y = acc[1] + ba.y;
        o0.z = acc[2] + ba.z; o0.w = acc[3] + ba.w;
        o1.x = acc[4] + bb.x; o1.y = acc[5] + bb.y;
        o1.z = acc[6] + bb.z; o1.w = acc[7] + bb.w;
        float* o = h2out + (size_t)wid * 64 + sub * 8;
        *(float4*)&o[0] = o0;
        *(float4*)&o[4] = o1;
    }
}

// ---------------- mean pool: one block per graph, contiguous node range ----------------

__global__ __launch_bounds__(256) void pool_kernel(const float* __restrict__ h2out,
                                                   const int* __restrict__ gstart,
                                                   float* __restrict__ pooled)
{
    __shared__ float sh[4][64];
    int g = blockIdx.x;
    int wv = threadIdx.x >> 6, lane = threadIdx.x & 63;
    int s = gstart[g], e = gstart[g + 1];
    float acc = 0.f;
    for (int n = s + wv; n < e; n += 4)
        acc += h2out[(size_t)n * 64 + lane];
    sh[wv][lane] = acc;
    __syncthreads();
    if (wv == 0) {
        float v = sh[0][lane] + sh[1][lane] + sh[2][lane] + sh[3][lane];
        float cnt = fmaxf((float)(e - s), 1.f);
        pooled[g * 64 + lane] = v / cnt;
    }
}

// ---------------- MLP head: one wave per graph ----------------

__global__ __launch_bounds__(64) void mlp_kernel(const float* __restrict__ pooled,
                                                 const float* __restrict__ Wl1,
                                                 const float* __restrict__ bl1,
                                                 const float* __restrict__ lng,
                                                 const float* __restrict__ lnb,
                                                 const float* __restrict__ Wl2,
                                                 const float* __restrict__ bl2,
                                                 float* __restrict__ out)
{
    int g = blockIdx.x, l = threadIdx.x;
    __shared__ float gs[64], zs[64];
    gs[l] = pooled[(size_t)g * 64 + l];
    __syncthreads();
    float z = bl1[l];
    for (int k = 0; k < 64; ++k) z = fmaf(gs[k], Wl1[k * 64 + l], z);
    z = fmaxf(z, 0.f);
    float sum = z;
    #pragma unroll
    for (int off = 32; off; off >>= 1) sum += __shfl_xor(sum, off);
    float mu = sum * (1.f / 64.f);
    float d  = z - mu;
    float vs = d * d;
    #pragma unroll
    for (int off = 32; off; off >>= 1) vs += __shfl_xor(vs, off);
    float var = vs * (1.f / 64.f);
    z = d * rsqrtf(var + 1e-5f) * lng[l] + lnb[l];
    zs[l] = z;
    __syncthreads();
    if (l < 16) {
        float o = bl2[l];
        for (int k = 0; k < 64; ++k) o = fmaf(zs[k], Wl2[k * 16 + l], o);
        out[g * 16 + l] = o;
    }
}

__global__ void copy_ea_kernel(const float* __restrict__ ea, float* __restrict__ out)
{
    for (int i = blockIdx.x * blockDim.x + threadIdx.x; i < N_EDGES; i += gridDim.x * blockDim.x)
        out[i] = ea[i];
}

// ---------------- launch ----------------

extern "C" void kernel_launch(void* const* d_in, const int* in_sizes, int n_in,
                              void* d_out, int out_size, void* d_ws, size_t ws_size,
                              hipStream_t stream)
{
    const float* x    = (const float*)d_in[0];
    const int*   ei   = (const int*)d_in[1];
    const float* ea   = (const float*)d_in[2];
    const int*   bidx = (const int*)d_in[3];
    const float* W1   = (const float*)d_in[4];
    const float* as1  = (const float*)d_in[5];
    const float* ad1  = (const float*)d_in[6];
    const float* We1  = (const float*)d_in[7];
    const float* ae1  = (const float*)d_in[8];
    const float* b1   = (const float*)d_in[9];
    const float* W2   = (const float*)d_in[10];
    const float* as2  = (const float*)d_in[11];
    const float* ad2  = (const float*)d_in[12];
    const float* We2  = (const float*)d_in[13];
    const float* ae2  = (const float*)d_in[14];
    const float* b2   = (const float*)d_in[15];
    const float* Wl1  = (const float*)d_in[16];
    const float* bl1  = (const float*)d_in[17];
    const float* lng  = (const float*)d_in[18];
    const float* lnb  = (const float*)d_in[19];
    const float* Wl2  = (const float*)d_in[20];
    const float* bl2  = (const float*)d_in[21];
    float* out = (float*)d_out;

    char* w = (char*)d_ws;
    float* scalars  = (float*)(w + 0);            // 64 B
    int*   deg      = (int*)  (w + 64);           // 200000 B
    const size_t zbytes = 200064;
    int*   rowstart = (int*)  (w + 200064);       // 200004 B (pad to 400128)
    int*   cursor   = (int*)  (w + 400128);       // 200000 B
    int*   gstart   = (int*)  (w + 600128);       // 516 B (pad to 600704)
    int*   csr_src  = (int*)  (w + 600704);       // 6.6 MB
    float* csr_ea   = (float*)(w + 7200704);      // 6.6 MB
    float* asrc1    = (float*)(w + 13800704);     // 800 KB
    float* adst1    = (float*)(w + 14600704);     // 800 KB
    float* asrc2    = (float*)(w + 15400704);     // 200 KB
    float* adst2    = (float*)(w + 15600704);     // 200 KB
    float* pooled   = (float*)(w + 15800704);     // 32 KB
    unsigned short* h1bf = (unsigned short*)(w + 15833472);   // 25.6 MB
    float* h1r      = (float*)(w + 41433472);     // 51.2 MB
    unsigned short* h2bf = (unsigned short*)(w + 92633472);   // 6.4 MB
    float* h2out    = (float*)(w + 99033472);     // 12.8 MB -> ends 111833472

    hipMemsetAsync(d_ws, 0, zbytes, stream);
    ea_sum_kernel<<<512, 256, 0, stream>>>(ea, scalars, N_EDGES);
    scalars_kernel<<<1, 64, 0, stream>>>(scalars, We1, ae1, We2, ae2);
    deg_kernel<<<1024, 256, 0, stream>>>(ei, deg);
    scan_kernel<<<1, 1024, 0, stream>>>(deg, rowstart, cursor);
    fill_kernel<<<1024, 256, 0, stream>>>(ei, ea, scalars, cursor, csr_src, csr_ea);
    gstart_kernel<<<1, 192, 0, stream>>>(bidx, gstart);

    { dim3 g(4, 782);  gemm_tile<16, true><<<g, 256, 0, stream>>>(x, W1, h1bf, N_NODES, 128, 256); }
    alphas1_kernel<<<12500, 256, 0, stream>>>(h1bf, as1, ad1, asrc1, adst1);
    agg1_kernel<<<12500, 256, 0, stream>>>(rowstart, csr_src, csr_ea, asrc1, adst1,
                                           scalars, h1bf, b1, h1r);
    { dim3 g(1, 782);  gemm_tile<16, true><<<g, 256, 0, stream>>>(h1r, W2, h2bf, N_NODES, 256, 64); }
    alphas2_kernel<<<12500, 256, 0, stream>>>(h2bf, as2, ad2, asrc2, adst2);
    agg2_kernel<<<12500, 256, 0, stream>>>(rowstart, csr_src, csr_ea, asrc2, adst2,
                                           scalars, h2bf, b2, h2out);
    pool_kernel<<<G_GRAPHS, 256, 0, stream>>>(h2out, gstart, pooled);
    mlp_kernel<<<G_GRAPHS, 64, 0, stream>>>(pooled, Wl1, bl1, lng, lnb, Wl2, bl2, out);
    copy_ea_kernel<<<2048, 256, 0, stream>>>(ea, out + 2048);
}